// Round 3
// baseline (1144.635 us; speedup 1.0000x reference)
//
#include <hip/hip_runtime.h>
#include <math.h>

#define S_LEN 4096
#define HDIM  64
#define WTOK  256      // attention window w
#define WIN   513      // 2w+1
#define NBH   32       // B*H

static constexpr size_t CTX_ELEMS = (size_t)NBH * S_LEN * HDIM;  // 8388608

// ---------------------------------------------------------------------------
// Kernel A: banded QK^T + softmax, writes attn_probs [NBH][S][513].
// grid = NBH * (S/64) = 2048 blocks, 256 threads (4 waves).
// Each wave owns 16 query rows; scores live in registers acc[16][9]:
// lane owns absolute key column (9 tiles of 64 keys cover the 528-wide
// union of the 16 rows' 513-wide windows). 16-row blocking halves K
// traffic vs 8-row (1.2 GB L2 ~ 35us, hidden under the 61us VALU floor).
// ---------------------------------------------------------------------------
__global__ __launch_bounds__(256) void qk_softmax_probs(
    const float* __restrict__ q, const float* __restrict__ k,
    float* __restrict__ probs)
{
    __shared__ float qs[64 * HDIM];   // 16 KB Q tile

    const int bid  = blockIdx.x;
    const int bh   = bid >> 6;
    const int q0   = (bid & 63) << 6;   // 64 query rows per block
    const int tid  = threadIdx.x;
    const int lane = tid & 63;
    const int wave = tid >> 6;

    const size_t bh_base = (size_t)bh * S_LEN * HDIM;

    // stage Q tile (coalesced float4)
    {
        const float4* src = reinterpret_cast<const float4*>(q + bh_base + (size_t)q0 * HDIM);
        float4* dst = reinterpret_cast<float4*>(qs);
        #pragma unroll
        for (int i = 0; i < 4; ++i) dst[tid + 256 * i] = src[tid + 256 * i];
    }
    __syncthreads();

    const float4* kbh4 = reinterpret_cast<const float4*>(k + bh_base);

    const int qr0 = q0 + wave * 16;      // wave's 16-row group

    // 9 key-tile pointers; lane owns key = qr0-256 + t*64 + lane
    const float4* kp[9];
    bool kok[9];
    #pragma unroll
    for (int t = 0; t < 9; ++t) {
        int key = qr0 - WTOK + t * 64 + lane;
        kok[t] = (key >= 0) && (key < S_LEN);
        int kc  = min(max(key, 0), S_LEN - 1);
        kp[t] = kbh4 + (size_t)kc * 16;
    }

    float acc[16][9];
    #pragma unroll
    for (int rr = 0; rr < 16; ++rr)
        #pragma unroll
        for (int t = 0; t < 9; ++t) acc[rr][t] = 0.0f;

    const float4* qrow = reinterpret_cast<const float4*>(qs + (wave * 16) * HDIM);

    for (int d4 = 0; d4 < 16; ++d4) {
        float4 kv[9];
        #pragma unroll
        for (int t = 0; t < 9; ++t) kv[t] = kp[t][d4];
        #pragma unroll
        for (int rr = 0; rr < 16; ++rr) {
            float4 qv = qrow[rr * 16 + d4];   // wave-uniform LDS broadcast
            #pragma unroll
            for (int t = 0; t < 9; ++t) {
                acc[rr][t] = fmaf(qv.x, kv[t].x, acc[rr][t]);
                acc[rr][t] = fmaf(qv.y, kv[t].y, acc[rr][t]);
                acc[rr][t] = fmaf(qv.z, kv[t].z, acc[rr][t]);
                acc[rr][t] = fmaf(qv.w, kv[t].w, acc[rr][t]);
            }
        }
    }

    const float scale = 0.125f;   // 1/sqrt(64)

    #pragma unroll
    for (int rr = 0; rr < 16; ++rr) {
        // band position of lane's key for row rr: j = t*64 + lane - rr
        float s[9];
        float m = -INFINITY;
        #pragma unroll
        for (int t = 0; t < 9; ++t) {
            int j = t * 64 + lane - rr;
            bool ok = kok[t] && (j >= 0) && (j <= 2 * WTOK);
            s[t] = ok ? acc[rr][t] * scale : -INFINITY;
            m = fmaxf(m, s[t]);
        }
        #pragma unroll
        for (int off = 32; off > 0; off >>= 1)
            m = fmaxf(m, __shfl_xor(m, off, 64));

        float z = 0.0f;
        #pragma unroll
        for (int t = 0; t < 9; ++t) {
            s[t] = __expf(s[t] - m);   // exp(-inf)=0 for masked entries
            z += s[t];
        }
        #pragma unroll
        for (int off = 32; off > 0; off >>= 1)
            z += __shfl_xor(z, off, 64);
        float inv = 1.0f / z;

        size_t base = ((size_t)bh * S_LEN + (qr0 + rr)) * WIN;
        #pragma unroll
        for (int t = 0; t < 9; ++t) {
            int j = t * 64 + lane - rr;
            if (j >= 0 && j <= 2 * WTOK)
                probs[base + j] = s[t] * inv;
        }
    }
}

// ---------------------------------------------------------------------------
// Kernel B: banded PV. context[row][d] = sum_j probs[row][j] * v[row-256+j][d]
// grid = NBH * (S/256) = 512 blocks, 256 threads (4 waves).
// Each wave owns a 64-row x 64-d output tile, 8x8 accumulators per lane.
// P staged transposed in wave-private LDS [32 keys][64 rows] (broadcast
// ds_read_b128, 2-way bank alias = free). V read straight from global:
// 8 lanes share each address -> one 256B line per key, reused by all 64
// rows in-register. No __syncthreads (wave-private LDS); wave_barrier()
// pins the compile-time order of ds_write -> cross-lane ds_read.
// ---------------------------------------------------------------------------
__global__ __launch_bounds__(256) void pv_banded(
    const float* __restrict__ probs, const float* __restrict__ v,
    float* __restrict__ ctx)
{
    __shared__ float pt[4][32 * 64];   // 32 KB total, per-wave private slices

    const int bid  = blockIdx.x;
    const int bh   = bid >> 4;
    const int tid  = threadIdx.x;
    const int lane = tid & 63;
    const int w    = tid >> 6;
    const int R0   = (bid & 15) * 256 + w * 64;  // wave's 64-row chunk
    const int rb   = lane >> 3;                  // row sub-block 0..7
    const int db   = lane & 7;                   // d   sub-block 0..7

    const float4* v4  = reinterpret_cast<const float4*>(v + (size_t)bh * S_LEN * HDIM);
    float*        ptw = pt[w];
    const float4* pt4 = reinterpret_cast<const float4*>(ptw);

    const int row_mine = R0 + lane;
    const float* prow = probs + ((size_t)bh * S_LEN + row_mine) * WIN;

    float acc[8][8];
    #pragma unroll
    for (int i = 0; i < 8; ++i)
        #pragma unroll
        for (int j = 0; j < 8; ++j) acc[i][j] = 0.0f;

    for (int t = 0; t < 18; ++t) {               // 18*32 = 576-key span
        const int kb = R0 - WTOK + t * 32;

        // stage P transposed: lane owns row R0+lane; key kb+c <-> j = kb+c-row+256
        const int j0 = kb - row_mine + WTOK;
        #pragma unroll
        for (int c = 0; c < 32; ++c) {
            int j = j0 + c;
            float pv = (j >= 0 && j <= 2 * WTOK) ? prow[j] : 0.0f;
            ptw[c * 64 + lane] = pv;             // conflict-free write
        }
        // cross-lane read of wave-private LDS: fence compiler reordering
        // (zero-cost scheduling barrier; HW DS ops are in-order per wave)
        __builtin_amdgcn_wave_barrier();

        #pragma unroll
        for (int kk = 0; kk < 32; ++kk) {
            int kc = min(max(kb + kk, 0), S_LEN - 1);   // wave-uniform
            const float4* vr = v4 + (size_t)kc * 16;
            float4 b0 = vr[db * 2];
            float4 b1 = vr[db * 2 + 1];
            float4 a0 = pt4[kk * 16 + rb * 2];
            float4 a1 = pt4[kk * 16 + rb * 2 + 1];
            float a[8] = {a0.x, a0.y, a0.z, a0.w, a1.x, a1.y, a1.z, a1.w};
            float b[8] = {b0.x, b0.y, b0.z, b0.w, b1.x, b1.y, b1.z, b1.w};
            #pragma unroll
            for (int ri = 0; ri < 8; ++ri)
                #pragma unroll
                for (int ci = 0; ci < 8; ++ci)
                    acc[ri][ci] = fmaf(a[ri], b[ci], acc[ri][ci]);
        }
        __builtin_amdgcn_wave_barrier();   // keep next tile's writes after reads
    }

    // write context: lane covers rows R0+rb*8..+7, cols db*8..+7
    float* cbh = ctx + (size_t)bh * S_LEN * HDIM;
    #pragma unroll
    for (int ri = 0; ri < 8; ++ri) {
        int row = R0 + rb * 8 + ri;
        float4 o0 = make_float4(acc[ri][0], acc[ri][1], acc[ri][2], acc[ri][3]);
        float4 o1 = make_float4(acc[ri][4], acc[ri][5], acc[ri][6], acc[ri][7]);
        float4* out4 = reinterpret_cast<float4*>(cbh + (size_t)row * HDIM + db * 8);
        out4[0] = o0;
        out4[1] = o1;
    }
}

// ---------------------------------------------------------------------------
extern "C" void kernel_launch(void* const* d_in, const int* in_sizes, int n_in,
                              void* d_out, int out_size, void* d_ws, size_t ws_size,
                              hipStream_t stream)
{
    const float* q = (const float*)d_in[0];
    const float* k = (const float*)d_in[1];
    const float* v = (const float*)d_in[2];
    (void)in_sizes; (void)n_in; (void)d_ws; (void)ws_size; (void)out_size;

    float* ctx   = (float*)d_out;               // [2,16,4096,64]
    float* probs = (float*)d_out + CTX_ELEMS;   // [32,4096,513]

    hipLaunchKernelGGL(qk_softmax_probs, dim3(NBH * 64), dim3(256), 0, stream,
                       q, k, probs);
    hipLaunchKernelGGL(pv_banded, dim3(NBH * 16), dim3(256), 0, stream,
                       probs, v, ctx);
}